// Round 4
// baseline (109.344 us; speedup 1.0000x reference)
//
#include <hip/hip_runtime.h>
#include <math.h>

// Problem constants
#define B_  2
#define S_  2048
#define D_  512
#define H_  8
#define DK_ 64
#define M_  (B_*S_)        // 4096
#define NBIG (M_*D_)       // 2097152 elems (query/key/value)
#define NW   (D_*D_)       // 262144 elems per weight

// q scale: 1/sqrt(DK) * log2(e), so softmax exp(x) becomes exp2(score*sph)
#define QSCALE 0.1803368801111214f

typedef __attribute__((ext_vector_type(8))) short bf16x8;
typedef __attribute__((ext_vector_type(4))) float f32x4;

__device__ inline unsigned short f2bf(float f) {
    union { float f; unsigned int u; } a; a.f = f;
    unsigned int u = a.u;
    u += 0x7FFFu + ((u >> 16) & 1u);   // RNE
    return (unsigned short)(u >> 16);
}

// async global->LDS, 16B per lane. LDS dest must be linear in lane id.
#define GLL(g, l) __builtin_amdgcn_global_load_lds( \
    (const __attribute__((address_space(1))) unsigned int*)(g), \
    (__attribute__((address_space(3))) unsigned int*)(l), 16, 0, 0)

__device__ inline void cvt8(const float* s, unsigned short* d) {
    const float4* sp = (const float4*)s;
    float4 v0 = sp[0], v1 = sp[1];
    union { bf16x8 v; unsigned short s[8]; } u;
    u.s[0]=f2bf(v0.x); u.s[1]=f2bf(v0.y); u.s[2]=f2bf(v0.z); u.s[3]=f2bf(v0.w);
    u.s[4]=f2bf(v1.x); u.s[5]=f2bf(v1.y); u.s[6]=f2bf(v1.z); u.s[7]=f2bf(v1.w);
    *(bf16x8*)d = u.v;
}

// ---------------------------------------------------------------------------
// fp32 -> bf16 conversion for query/key/value and the 4 weight matrices.
// ---------------------------------------------------------------------------
__global__ __launch_bounds__(256) void cvt7_kernel(
    const float* __restrict__ q, const float* __restrict__ k, const float* __restrict__ v,
    const float* __restrict__ wq, const float* __restrict__ wk,
    const float* __restrict__ wv, const float* __restrict__ wo,
    unsigned short* __restrict__ qB, unsigned short* __restrict__ kB,
    unsigned short* __restrict__ vB, unsigned short* __restrict__ WB)
{
    int e = (blockIdx.x * 256 + threadIdx.x) * 8;
    if (e < NBIG)            cvt8(q + e, qB + e);
    else if (e < 2*NBIG)     cvt8(k + (e - NBIG), kB + (e - NBIG));
    else if (e < 3*NBIG)     cvt8(v + (e - 2*NBIG), vB + (e - 2*NBIG));
    else {
        int w = e - 3*NBIG;            // 0 .. 4*NW
        int wi = w >> 18;              // NW = 2^18
        int off = w & (NW - 1);
        const float* src = wi == 0 ? wq : wi == 1 ? wk : wi == 2 ? wv : wo;
        cvt8(src + off, WB + w);
    }
}

// ---------------------------------------------------------------------------
// Fused Q/K/V projection GEMM, double-buffered global_load_lds, 1 barrier/iter.
// Grid (192, 8): blockIdx.x = seg*64 + row-tile, seg 0/1/2 = q/k/v.
// Tile 64x64, BK=32, 4 waves (2x2).
// seg 0: bf16 [B,H,S,DK], scaled by QSCALE.  seg 1: bf16 [B,H,S,DK].
// seg 2: bf16 [B,H,DK,S] (V transposed).
// ---------------------------------------------------------------------------
__global__ __launch_bounds__(256) void qkv_gemm(
    const unsigned short* __restrict__ qB, const unsigned short* __restrict__ kB,
    const unsigned short* __restrict__ vB, const unsigned short* __restrict__ WB,
    const float* __restrict__ bq, const float* __restrict__ bk, const float* __restrict__ bv,
    unsigned short* __restrict__ q_ws, unsigned short* __restrict__ k_ws,
    unsigned short* __restrict__ vT_ws)
{
    __shared__ unsigned short A_lds[2][64][32];
    __shared__ unsigned short B_lds[2][64][32];

    const int t    = threadIdx.x;
    const int lane = t & 63;
    const int wave = t >> 6;
    const int wm   = wave >> 1, wn = wave & 1;
    const int lrow = lane & 15, lgr = lane >> 4;
    const int seg  = blockIdx.x >> 6;
    const int bm   = blockIdx.x & 63;
    const int bn   = blockIdx.y;

    const unsigned short* A    = seg == 0 ? qB : seg == 1 ? kB : vB;
    const unsigned short* W    = WB + (size_t)seg * NW;
    const float*          bias = seg == 0 ? bq : seg == 1 ? bk : bv;
    unsigned short*       Cp   = seg == 0 ? q_ws : seg == 1 ? k_ws : vT_ws;

    f32x4 acc[2][2] = {};

    const unsigned short* Ag = A + (size_t)(bm*64 + (t>>2))*512 + (t&3)*8;
    const unsigned short* Wg = W + (size_t)(bn*64 + (t>>2))*512 + (t&3)*8;
    unsigned short* lA0 = &A_lds[0][t>>2][(t&3)*8];
    unsigned short* lA1 = &A_lds[1][t>>2][(t&3)*8];
    unsigned short* lB0 = &B_lds[0][t>>2][(t&3)*8];
    unsigned short* lB1 = &B_lds[1][t>>2][(t&3)*8];

    GLL(Ag, lA0);
    GLL(Wg, lB0);

    for (int kk = 0; kk < 512; kk += 32) {
        const int buf = (kk >> 5) & 1;
        __syncthreads();   // drains vmcnt -> buf ready (loads issued 1 phase ago)
        if (kk < 480) {
            GLL(Ag + kk + 32, buf ? lA0 : lA1);
            GLL(Wg + kk + 32, buf ? lB0 : lB1);
        }

        bf16x8 a0 = *(const bf16x8*)&A_lds[buf][wm*32 +      lrow][lgr*8];
        bf16x8 a1 = *(const bf16x8*)&A_lds[buf][wm*32 + 16 + lrow][lgr*8];
        bf16x8 b0 = *(const bf16x8*)&B_lds[buf][wn*32 +      lrow][lgr*8];
        bf16x8 b1 = *(const bf16x8*)&B_lds[buf][wn*32 + 16 + lrow][lgr*8];

        acc[0][0] = __builtin_amdgcn_mfma_f32_16x16x32_bf16(a0, b0, acc[0][0], 0, 0, 0);
        acc[0][1] = __builtin_amdgcn_mfma_f32_16x16x32_bf16(a0, b1, acc[0][1], 0, 0, 0);
        acc[1][0] = __builtin_amdgcn_mfma_f32_16x16x32_bf16(a1, b0, acc[1][0], 0, 0, 0);
        acc[1][1] = __builtin_amdgcn_mfma_f32_16x16x32_bf16(a1, b1, acc[1][1], 0, 0, 0);
    }

    #pragma unroll
    for (int mf = 0; mf < 2; ++mf)
    #pragma unroll
    for (int nf = 0; nf < 2; ++nf)
    #pragma unroll
    for (int r = 0; r < 4; ++r) {
        int grow = bm*64 + wm*32 + mf*16 + lgr*4 + r;
        int gcol = bn*64 + wn*32 + nf*16 + lrow;
        float v = acc[mf][nf][r] + bias[gcol];
        if (seg == 0) v *= QSCALE;
        int bb = grow >> 11, s = grow & 2047;
        int hh = gcol >> 6,  dk = gcol & 63;
        unsigned short bv16 = f2bf(v);
        if (seg < 2)
            Cp[((size_t)(bb*H_ + hh)*S_ + s)*DK_ + dk] = bv16;
        else
            Cp[((size_t)(bb*H_ + hh)*DK_ + dk)*S_ + s] = bv16;
    }
}

// ---------------------------------------------------------------------------
// Output projection GEMM: fp32 out = attn(bf16) @ Wo^T + bo. Same dbuf structure.
// ---------------------------------------------------------------------------
__global__ __launch_bounds__(256) void out_gemm(
    const unsigned short* __restrict__ A,
    const unsigned short* __restrict__ W,
    const float* __restrict__ bias,
    float* __restrict__ C)
{
    __shared__ unsigned short A_lds[2][64][32];
    __shared__ unsigned short B_lds[2][64][32];

    const int t    = threadIdx.x;
    const int lane = t & 63;
    const int wave = t >> 6;
    const int wm   = wave >> 1, wn = wave & 1;
    const int lrow = lane & 15, lgr = lane >> 4;
    const int bm   = blockIdx.x, bn = blockIdx.y;

    f32x4 acc[2][2] = {};

    const unsigned short* Ag = A + (size_t)(bm*64 + (t>>2))*512 + (t&3)*8;
    const unsigned short* Wg = W + (size_t)(bn*64 + (t>>2))*512 + (t&3)*8;
    unsigned short* lA0 = &A_lds[0][t>>2][(t&3)*8];
    unsigned short* lA1 = &A_lds[1][t>>2][(t&3)*8];
    unsigned short* lB0 = &B_lds[0][t>>2][(t&3)*8];
    unsigned short* lB1 = &B_lds[1][t>>2][(t&3)*8];

    GLL(Ag, lA0);
    GLL(Wg, lB0);

    for (int kk = 0; kk < 512; kk += 32) {
        const int buf = (kk >> 5) & 1;
        __syncthreads();
        if (kk < 480) {
            GLL(Ag + kk + 32, buf ? lA0 : lA1);
            GLL(Wg + kk + 32, buf ? lB0 : lB1);
        }

        bf16x8 a0 = *(const bf16x8*)&A_lds[buf][wm*32 +      lrow][lgr*8];
        bf16x8 a1 = *(const bf16x8*)&A_lds[buf][wm*32 + 16 + lrow][lgr*8];
        bf16x8 b0 = *(const bf16x8*)&B_lds[buf][wn*32 +      lrow][lgr*8];
        bf16x8 b1 = *(const bf16x8*)&B_lds[buf][wn*32 + 16 + lrow][lgr*8];

        acc[0][0] = __builtin_amdgcn_mfma_f32_16x16x32_bf16(a0, b0, acc[0][0], 0, 0, 0);
        acc[0][1] = __builtin_amdgcn_mfma_f32_16x16x32_bf16(a0, b1, acc[0][1], 0, 0, 0);
        acc[1][0] = __builtin_amdgcn_mfma_f32_16x16x32_bf16(a1, b0, acc[1][0], 0, 0, 0);
        acc[1][1] = __builtin_amdgcn_mfma_f32_16x16x32_bf16(a1, b1, acc[1][1], 0, 0, 0);
    }

    #pragma unroll
    for (int mf = 0; mf < 2; ++mf)
    #pragma unroll
    for (int nf = 0; nf < 2; ++nf)
    #pragma unroll
    for (int r = 0; r < 4; ++r) {
        int grow = bm*64 + wm*32 + mf*16 + lgr*4 + r;
        int gcol = bn*64 + wn*32 + nf*16 + lrow;
        C[(size_t)grow*512 + gcol] = acc[mf][nf][r] + bias[gcol];
    }
}

// ---------------------------------------------------------------------------
// Attention, no-max softmax via exp2 (log2e folded into Q scale).
// Split-K across wave halves, 512 threads = 8 waves, pad-68 LDS (52.7 KB ->
// 3 blocks/CU). Per-iter: 0 cross-lane ops, 2 barriers.
// ---------------------------------------------------------------------------
__global__ __launch_bounds__(512, 6) void attn_fast(
    const unsigned short* __restrict__ q_ws,
    const unsigned short* __restrict__ k_ws,
    const unsigned short* __restrict__ vT_ws,
    const float* __restrict__ sph,
    unsigned short* __restrict__ attn_ws)
{
    __shared__ unsigned short K_lds[2][64][68];
    __shared__ unsigned short V_lds[2][64][68];
    __shared__ unsigned short P_lds[8][16][68];
    __shared__ float l_sh[8][16];
    // O_sh overlays K_lds (dead after main loop): 4*16*68*4 = 17408 = sizeof(K_lds)
    float (*O_sh)[16][68] = (float (*)[16][68])(&K_lds[0][0][0]);

    const int t    = threadIdx.x;
    const int lane = t & 63, wave = t >> 6;
    const int lrow = lane & 15, lgr = lane >> 4;
    const int wq = wave & 3;      // q sub-tile (16 rows)
    const int wh = wave >> 2;     // k half
    const int qt = blockIdx.x, bh = blockIdx.y;
    const int b  = bh >> 3;
    const int h  = bh & 7;
    const int qbase = qt * 64;
    const size_t head_off = (size_t)bh * S_ * DK_;

    bf16x8 qf0, qf1;
    {
        const unsigned short* qp =
            q_ws + head_off + (size_t)(qbase + wq*16 + lrow)*DK_ + lgr*8;
        qf0 = *(const bf16x8*)qp;
        qf1 = *(const bf16x8*)(qp + 32);
    }

    const int sh = t >> 8;
    const int sr = (t >> 2) & 63;
    const int sc = (t & 3) * 16;
    const unsigned short* kstage = k_ws  + head_off + ((size_t)sh*1024 + sr)*DK_ + sc;
    const unsigned short* vstage = vT_ws + head_off + (size_t)sr*S_ + sh*1024 + sc;

    const float* sphb   = sph + (size_t)b * S_ * S_;
    const float* sph_p0 = sphb + (size_t)(qbase + wq*16 + lgr*4 + 0)*S_ + wh*1024 + lrow;
    const float* sph_p1 = sph_p0 + S_;
    const float* sph_p2 = sph_p0 + 2*S_;
    const float* sph_p3 = sph_p0 + 3*S_;

    f32x4 acc_o[4] = {};
    float psum[4] = {0.f, 0.f, 0.f, 0.f};

    // prologue: stage tile 0 + sph tile 0
    bf16x8 kr0 = *(const bf16x8*)(kstage);
    bf16x8 kr1 = *(const bf16x8*)(kstage + 8);
    bf16x8 vr0 = *(const bf16x8*)(vstage);
    bf16x8 vr1 = *(const bf16x8*)(vstage + 8);
    *(bf16x8*)&K_lds[sh][sr][sc]     = kr0;
    *(bf16x8*)&K_lds[sh][sr][sc + 8] = kr1;
    *(bf16x8*)&V_lds[sh][sr][sc]     = vr0;
    *(bf16x8*)&V_lds[sh][sr][sc + 8] = vr1;

    float sphr[4][4];
    #pragma unroll
    for (int nf = 0; nf < 4; ++nf) {
        sphr[nf][0] = sph_p0[nf*16];
        sphr[nf][1] = sph_p1[nf*16];
        sphr[nf][2] = sph_p2[nf*16];
        sphr[nf][3] = sph_p3[nf*16];
    }

    for (int kt = 0; kt < 16; ++kt) {
        __syncthreads();   // LDS tile kt ready

        if (kt < 15) {     // next-tile K/V register prefetch
            const unsigned short* kp = kstage + (size_t)(kt+1)*64*DK_;
            const unsigned short* vp = vstage + (kt+1)*64;
            kr0 = *(const bf16x8*)(kp);
            kr1 = *(const bf16x8*)(kp + 8);
            vr0 = *(const bf16x8*)(vp);
            vr1 = *(const bf16x8*)(vp + 8);
        }

        // QK^T: 16 q rows x 64 k cols per wave
        f32x4 sc4[4];
        #pragma unroll
        for (int nf = 0; nf < 4; ++nf) {
            bf16x8 kf0 = *(const bf16x8*)&K_lds[wh][nf*16 + lrow][lgr*8];
            bf16x8 kf1 = *(const bf16x8*)&K_lds[wh][nf*16 + lrow][32 + lgr*8];
            f32x4 a = {};
            a = __builtin_amdgcn_mfma_f32_16x16x32_bf16(qf0, kf0, a, 0, 0, 0);
            a = __builtin_amdgcn_mfma_f32_16x16x32_bf16(qf1, kf1, a, 0, 0, 0);
            sc4[nf] = a;
        }

        // p = exp2(score * sph)  (score pre-scaled by log2e/8); row-sum partials
        #pragma unroll
        for (int nf = 0; nf < 4; ++nf)
        #pragma unroll
        for (int r = 0; r < 4; ++r) {
            float p = __builtin_amdgcn_exp2f(sc4[nf][r] * sphr[nf][r]);
            sc4[nf][r] = p;
            psum[r] += p;
        }

        // P -> bf16 -> per-wave LDS (wave-private: no barrier needed)
        #pragma unroll
        for (int nf = 0; nf < 4; ++nf)
        #pragma unroll
        for (int r = 0; r < 4; ++r)
            P_lds[wave][lgr*4 + r][nf*16 + lrow] = f2bf(sc4[nf][r]);

        if (kt < 15) {     // next-tile sph prefetch (hides under PV)
            const int off = (kt + 1) * 64;
            #pragma unroll
            for (int nf = 0; nf < 4; ++nf) {
                sphr[nf][0] = sph_p0[off + nf*16];
                sphr[nf][1] = sph_p1[off + nf*16];
                sphr[nf][2] = sph_p2[off + nf*16];
                sphr[nf][3] = sph_p3[off + nf*16];
            }
        }

        // PV: acc_o[nb] += P @ V  (unnormalized accumulate)
        #pragma unroll
        for (int ks2 = 0; ks2 < 2; ++ks2) {
            bf16x8 pf = *(const bf16x8*)&P_lds[wave][lrow][ks2*32 + lgr*8];
            #pragma unroll
            for (int nb = 0; nb < 4; ++nb) {
                bf16x8 vf = *(const bf16x8*)&V_lds[wh][nb*16 + lrow][ks2*32 + lgr*8];
                acc_o[nb] = __builtin_amdgcn_mfma_f32_16x16x32_bf16(pf, vf, acc_o[nb], 0, 0, 0);
            }
        }
        __syncthreads();   // all K/V_lds reads done

        if (kt < 15) {
            *(bf16x8*)&K_lds[sh][sr][sc]     = kr0;
            *(bf16x8*)&K_lds[sh][sr][sc + 8] = kr1;
            *(bf16x8*)&V_lds[sh][sr][sc]     = vr0;
            *(bf16x8*)&V_lds[sh][sr][sc + 8] = vr1;
        }
    }

    // one-time row-sum reduce (over lrow lanes within each lgr group)
    #pragma unroll
    for (int off = 1; off < 16; off <<= 1)
        #pragma unroll
        for (int r = 0; r < 4; ++r)
            psum[r] += __shfl_xor(psum[r], off, 64);

    if (lrow == 0) {
        #pragma unroll
        for (int r = 0; r < 4; ++r)
            l_sh[wave][lgr*4 + r] = psum[r];
    }
    __syncthreads();

    float linv[4];
    #pragma unroll
    for (int r = 0; r < 4; ++r) {
        int row = lgr*4 + r;
        linv[r] = 1.f / (l_sh[wq][row] + l_sh[wq + 4][row]);
    }
    if (wh == 1) {
        #pragma unroll
        for (int nb = 0; nb < 4; ++nb)
        #pragma unroll
        for (int r = 0; r < 4; ++r)
            O_sh[wq][lgr*4 + r][nb*16 + lrow] = acc_o[nb][r];
    }
    __syncthreads();
    if (wh == 0) {
        #pragma unroll
        for (int nb = 0; nb < 4; ++nb)
        #pragma unroll
        for (int r = 0; r < 4; ++r) {
            int qrow = qbase + wq*16 + lgr*4 + r;
            float o = (acc_o[nb][r] + O_sh[wq][lgr*4 + r][nb*16 + lrow]) * linv[r];
            attn_ws[((size_t)(b*S_) + qrow)*D_ + h*64 + nb*16 + lrow] = f2bf(o);
        }
    }
}

// ===========================================================================
// Fallback path (R2, proven): used only if ws_size < 26 MiB.
// ===========================================================================
template<int A_BF16, int MODE>
__global__ __launch_bounds__(256) void gemm_old(
    const void* __restrict__ Aptr,
    const float* __restrict__ W,
    const float* __restrict__ bias,
    void* __restrict__ Cptr)
{
    __shared__ unsigned short A_lds[64][40];
    __shared__ unsigned short B_lds[64][40];

    const int t    = threadIdx.x;
    const int lane = t & 63;
    const int wave = t >> 6;
    const int wm   = wave >> 1, wn = wave & 1;
    const int lrow = lane & 15, lgr = lane >> 4;
    const int bm   = blockIdx.x, bn = blockIdx.y;

    f32x4 acc[2][2] = {};
    const int srow = t >> 2;
    const int scol = (t & 3) * 8;

    for (int kk = 0; kk < 512; kk += 32) {
        if (A_BF16) {
            const unsigned short* A = (const unsigned short*)Aptr;
            bf16x8 v = *(const bf16x8*)(A + (size_t)(bm*64 + srow)*512 + kk + scol);
            *(bf16x8*)&A_lds[srow][scol] = v;
        } else {
            const float* A = (const float*)Aptr;
            cvt8(A + (size_t)(bm*64 + srow)*512 + kk + scol, &A_lds[srow][scol]);
        }
        cvt8(W + (size_t)(bn*64 + srow)*512 + kk + scol, &B_lds[srow][scol]);
        __syncthreads();

        bf16x8 a0 = *(const bf16x8*)&A_lds[wm*32 +      lrow][lgr*8];
        bf16x8 a1 = *(const bf16x8*)&A_lds[wm*32 + 16 + lrow][lgr*8];
        bf16x8 b0 = *(const bf16x8*)&B_lds[wn*32 +      lrow][lgr*8];
        bf16x8 b1 = *(const bf16x8*)&B_lds[wn*32 + 16 + lrow][lgr*8];

        acc[0][0] = __builtin_amdgcn_mfma_f32_16x16x32_bf16(a0, b0, acc[0][0], 0, 0, 0);
        acc[0][1] = __builtin_amdgcn_mfma_f32_16x16x32_bf16(a0, b1, acc[0][1], 0, 0, 0);
        acc[1][0] = __builtin_amdgcn_mfma_f32_16x16x32_bf16(a1, b0, acc[1][0], 0, 0, 0);
        acc[1][1] = __builtin_amdgcn_mfma_f32_16x16x32_bf16(a1, b1, acc[1][1], 0, 0, 0);
        __syncthreads();
    }

    #pragma unroll
    for (int mf = 0; mf < 2; ++mf)
    #pragma unroll
    for (int nf = 0; nf < 2; ++nf)
    #pragma unroll
    for (int r = 0; r < 4; ++r) {
        int grow = bm*64 + wm*32 + mf*16 + lgr*4 + r;
        int gcol = bn*64 + wn*32 + nf*16 + lrow;
        float v = acc[mf][nf][r] + bias[gcol];
        if (MODE == 2) {
            ((float*)Cptr)[(size_t)grow*512 + gcol] = v;
        } else {
            int bb = grow >> 11, s = grow & 2047;
            int hh = gcol >> 6,  dk = gcol & 63;
            unsigned short bv = f2bf(v);
            if (MODE == 0)
                ((unsigned short*)Cptr)[((size_t)(bb*H_ + hh)*S_ + s)*DK_ + dk] = bv;
            else
                ((unsigned short*)Cptr)[((size_t)(bb*H_ + hh)*DK_ + dk)*S_ + s] = bv;
        }
    }
}

__global__ __launch_bounds__(512, 4) void attn_old(
    const unsigned short* __restrict__ q_ws,
    const unsigned short* __restrict__ k_ws,
    const unsigned short* __restrict__ vT_ws,
    const float* __restrict__ sph,
    unsigned short* __restrict__ attn_ws)
{
    __shared__ unsigned short K_lds[2][64][72];
    __shared__ unsigned short V_lds[2][64][72];
    __shared__ unsigned short P_lds[8][16][72];
    __shared__ float m_sh[8][16];
    __shared__ float l_sh[8][16];
    __shared__ float O_sh[4][16][68];

    const int t    = threadIdx.x;
    const int lane = t & 63, wave = t >> 6;
    const int lrow = lane & 15, lgr = lane >> 4;
    const int wq = wave & 3;
    const int wh = wave >> 2;
    const int qt = blockIdx.x, bh = blockIdx.y;
    const int b  = bh >> 3;
    const int h  = bh & 7;
    const int qbase = qt * 64;
    const size_t head_off = (size_t)bh * S_ * DK_;

    bf16x8 qf0, qf1;
    {
        const unsigned short* qp =
            q_ws + head_off + (size_t)(qbase + wq*16 + lrow)*DK_ + lgr*8;
        qf0 = *(const bf16x8*)qp;
        qf1 = *(const bf16x8*)(qp + 32);
    }

    const int sh = t >> 8;
    const int sr = (t >> 2) & 63;
    const int sc = (t & 3) * 16;
    const unsigned short* kstage = k_ws  + head_off + ((size_t)sh*1024 + sr)*DK_ + sc;
    const unsigned short* vstage = vT_ws + head_off + (size_t)sr*S_ + sh*1024 + sc;

    const float* sphb   = sph + (size_t)b * S_ * S_;
    const float* sph_p0 = sphb + (size_t)(qbase + wq*16 + lgr*4 + 0)*S_ + wh*1024 + lrow;
    const float* sph_p1 = sph_p0 + S_;
    const float* sph_p2 = sph_p0 + 2*S_;
    const float* sph_p3 = sph_p0 + 3*S_;

    f32x4 acc_o[4] = {};
    float m_run[4] = {-INFINITY,-INFINITY,-INFINITY,-INFINITY};
    float l_run[4] = {0.f,0.f,0.f,0.f};

    bf16x8 kr0 = *(const bf16x8*)(kstage);
    bf16x8 kr1 = *(const bf16x8*)(kstage + 8);
    bf16x8 vr0 = *(const bf16x8*)(vstage);
    bf16x8 vr1 = *(const bf16x8*)(vstage + 8);
    *(bf16x8*)&K_lds[sh][sr][sc]     = kr0;
    *(bf16x8*)&K_lds[sh][sr][sc + 8] = kr1;
    *(bf16x8*)&V_lds[sh][sr][sc]     = vr0;
    *(bf16x8*)&V_lds[sh][sr][sc + 8] = vr1;

    float sphr[4][4];
    #pragma unroll
    for (int nf = 0; nf < 4; ++nf) {
        sphr[nf][0] = sph_p0[nf*16];
        sphr[nf][1] = sph_p1[nf*16];
        sphr[nf][2] = sph_p2[nf*16];
        sphr[nf][3] = sph_p3[nf*16];
    }

    for (int kt = 0; kt < 16; ++kt) {
        __syncthreads();

        if (kt < 15) {
            const unsigned short* kp = kstage + (size_t)(kt+1)*64*DK_;
            const unsigned short* vp = vstage + (kt+1)*64;
            kr0 = *(const bf16x8*)(kp);
            kr1 = *(const bf16x8*)(kp + 8);
            vr0 = *(const bf16x8*)(vp);
            vr1 = *(const bf16x8*)(vp + 8);
        }

        f32x4 sc4[4];
        #pragma unroll
        for (int nf = 0; nf < 4; ++nf) {
            bf16x8 kf0 = *(const bf16x8*)&K_lds[wh][nf*16 + lrow][lgr*8];
            bf16x8 kf1 = *(const bf16x8*)&K_lds[wh][nf*16 + lrow][32 + lgr*8];
            f32x4 a = {};
            a = __builtin_amdgcn_mfma_f32_16x16x32_bf16(qf0, kf0, a, 0, 0, 0);
            a = __builtin_amdgcn_mfma_f32_16x16x32_bf16(qf1, kf1, a, 0, 0, 0);
            sc4[nf] = a;
        }

        float pmax[4] = {-INFINITY,-INFINITY,-INFINITY,-INFINITY};
        #pragma unroll
        for (int nf = 0; nf < 4; ++nf)
        #pragma unroll
        for (int r = 0; r < 4; ++r) {
            float s = sc4[nf][r] * 0.125f * sphr[nf][r];
            sc4[nf][r] = s;
            pmax[r] = fmaxf(pmax[r], s);
        }
        #pragma unroll
        for (int off = 1; off < 16; off <<= 1)
            #pragma unroll
            for (int r = 0; r < 4; ++r)
                pmax[r] = fmaxf(pmax[r], __shfl_xor(pmax[r], off, 64));

        float sc_old[4], psum[4] = {0.f,0.f,0.f,0.f};
        #pragma unroll
        for (int r = 0; r < 4; ++r) {
            float mn = fmaxf(m_run[r], pmax[r]);
            sc_old[r] = __expf(m_run[r] - mn);
            m_run[r] = mn;
        }
        #pragma unroll
        for (int nf = 0; nf < 4; ++nf)
        #pragma unroll
        for (int r = 0; r < 4; ++r) {
            float p = __expf(sc4[nf][r] - m_run[r]);
            sc4[nf][r] = p;
            psum[r] += p;
        }
        #pragma unroll
        for (int off = 1; off < 16; off <<= 1)
            #pragma unroll
            for (int r = 0; r < 4; ++r)
                psum[r] += __shfl_xor(psum[r], off, 64);
        #pragma unroll
        for (int r = 0; r < 4; ++r)
            l_run[r] = l_run[r] * sc_old[r] + psum[r];
        #pragma unroll
        for (int nb = 0; nb < 4; ++nb)
            #pragma unroll
            for (int r = 0; r < 4; ++r)
                acc_o[nb][r] *= sc_old[r];

        #pragma unroll
        for (int nf = 0; nf < 4; ++nf)
        #pragma unroll
        for (int r = 0; r < 4; ++r)
            P_lds[wave][lgr*4 + r][nf*16 + lrow] = f2bf(sc4[nf][r]);
        __syncthreads();

        #pragma unroll
        for (int ks2 = 0; ks2 < 2; ++ks2) {
            bf16x8 pf = *(const bf16x8*)&P_lds[wave][lrow][ks2*32 + lgr*8];
            #pragma unroll
            for (int nb = 0; nb < 4; ++nb) {
                bf16x8 vf = *(const bf16x8*)&V_lds[wh][nb*16 + lrow][ks2*32 + lgr*8];
                acc_o[nb] = __builtin_amdgcn_mfma_f32_16x16x32_bf16(pf, vf, acc_o[nb], 0, 0, 0);
            }
        }

        if (kt < 15) {
            const int off = (kt + 1) * 64;
            #pragma unroll
            for (int nf = 0; nf < 4; ++nf) {
                sphr[nf][0] = sph_p0[off + nf*16];
                sphr[nf][1] = sph_p1[off + nf*16];
                sphr[nf][2] = sph_p2[off + nf*16];
                sphr[nf][3] = sph_p3[off + nf*16];
            }
        }
        __syncthreads();

        if (kt < 15) {
            *(bf16x8*)&K_lds[sh][sr][sc]     = kr0;
            *(bf16x8*)&K_lds[sh][sr][sc + 8] = kr1;
            *(bf16x8*)&V_lds[sh][sr][sc]     = vr0;
            *(bf16x8*)&V_lds[sh][sr][sc + 8] = vr1;
        }
    }

    if (lrow == 0) {
        #pragma unroll
        for (int r = 0; r < 4; ++r) {
            m_sh[wave][lgr*4 + r] = m_run[r];
            l_sh[wave][lgr*4 + r] = l_run[r];
        }
    }
    __syncthreads();

    float scl[4], lcomb[4];
    #pragma unroll
    for (int r = 0; r < 4; ++r) {
        int row = lgr*4 + r;
        float m0 = m_sh[wq][row],     m1 = m_sh[wq + 4][row];
        float l0 = l_sh[wq][row],     l1 = l_sh[wq + 4][row];
        float mm = fmaxf(m0, m1);
        float s0 = __expf(m0 - mm),   s1 = __expf(m1 - mm);
        lcomb[r] = l0*s0 + l1*s1;
        scl[r]   = (wh == 0) ? s0 : s1;
    }
    if (wh == 1) {
        #pragma unroll
        for (int nb = 0; nb < 4; ++nb)
        #pragma unroll
        for (int r = 0; r < 4; ++r)
            O_sh[wq][lgr*4 + r][nb*16 + lrow] = acc_o[nb][r] * scl[r];
    }
    __syncthreads();
    if (wh == 0) {
        #pragma unroll
        for (int nb = 0; nb < 4; ++nb)
        #pragma unroll
        for (int r = 0; r < 4; ++r) {
            int qrow = qbase + wq*16 + lgr*4 + r;
            float o = (acc_o[nb][r]*scl[r] + O_sh[wq][lgr*4 + r][nb*16 + lrow]) / lcomb[r];
            attn_ws[((size_t)(b*S_) + qrow)*D_ + h*64 + nb*16 + lrow] = f2bf(o);
        }
    }
}

// ---------------------------------------------------------------------------
extern "C" void kernel_launch(void* const* d_in, const int* in_sizes, int n_in,
                              void* d_out, int out_size, void* d_ws, size_t ws_size,
                              hipStream_t stream) {
    (void)in_sizes; (void)n_in; (void)out_size;
    const float* query = (const float*)d_in[0];
    const float* key_  = (const float*)d_in[1];
    const float* value = (const float*)d_in[2];
    const float* sph   = (const float*)d_in[3];
    const float* Wq = (const float*)d_in[4];
    const float* bq = (const float*)d_in[5];
    const float* Wk = (const float*)d_in[6];
    const float* bk = (const float*)d_in[7];
    const float* Wv = (const float*)d_in[8];
    const float* bv = (const float*)d_in[9];
    const float* Wo = (const float*)d_in[10];
    const float* bo = (const float*)d_in[11];

    char* ws = (char*)d_ws;
    const size_t MB = 1024*1024;
    const size_t NEED = 26*MB;

    if (ws_size >= NEED) {
        // layout: [0 qB/attn_ws][4 kB][8 vB][12 WB(2MB)][14 q_ws][18 k_ws][22 vT_ws]
        unsigned short* qB      = (unsigned short*)(ws);
        unsigned short* kB      = (unsigned short*)(ws + 4*MB);
        unsigned short* vB      = (unsigned short*)(ws + 8*MB);
        unsigned short* WB      = (unsigned short*)(ws + 12*MB);
        unsigned short* q_ws    = (unsigned short*)(ws + 14*MB);
        unsigned short* k_ws    = (unsigned short*)(ws + 18*MB);
        unsigned short* vT_ws   = (unsigned short*)(ws + 22*MB);
        unsigned short* attn_ws = qB;   // qB dead after its GEMM

        cvt7_kernel<<<3584, 256, 0, stream>>>(query, key_, value, Wq, Wk, Wv, Wo,
                                              qB, kB, vB, WB);
        qkv_gemm<<<dim3(192, 8), 256, 0, stream>>>(qB, kB, vB, WB, bq, bk, bv,
                                                   q_ws, k_ws, vT_ws);
        attn_fast<<<dim3(S_/64, B_*H_), 512, 0, stream>>>(q_ws, k_ws, vT_ws, sph, attn_ws);
        out_gemm<<<dim3(64, 8), 256, 0, stream>>>(attn_ws, WB + 3*(size_t)NW, bo, (float*)d_out);
    } else {
        // R2 fallback (needs 16 MiB)
        const size_t SEG = (size_t)M_ * D_ * 2;
        unsigned short* q_ws    = (unsigned short*)(ws);
        unsigned short* k_ws    = (unsigned short*)(ws + SEG);
        unsigned short* vT_ws   = (unsigned short*)(ws + 2*SEG);
        unsigned short* attn_ws = (unsigned short*)(ws + 3*SEG);

        dim3 gg(M_/64, D_/64);
        gemm_old<0, 0><<<gg, 256, 0, stream>>>(query, Wq, bq, q_ws);
        gemm_old<0, 0><<<gg, 256, 0, stream>>>(key_,  Wk, bk, k_ws);
        gemm_old<0, 1><<<gg, 256, 0, stream>>>(value, Wv, bv, vT_ws);
        attn_old<<<dim3(S_/64, B_*H_), 512, 0, stream>>>(q_ws, k_ws, vT_ws, sph, attn_ws);
        gemm_old<1, 2><<<gg, 256, 0, stream>>>(attn_ws, Wo, bo, (float*)d_out);
    }
}

// Round 5
// 83.028 us; speedup vs baseline: 1.3170x; 1.3170x over previous
//
#include <hip/hip_runtime.h>
#include <math.h>

// Problem constants
#define B_  2
#define S_  2048
#define D_  512
#define H_  8
#define DK_ 64
#define M_  (B_*S_)        // 4096
#define NBIG (M_*D_)       // 2097152 elems (query/key/value)
#define NW   (D_*D_)       // 262144 elems per weight

// q scale: 1/sqrt(DK) * log2(e), so softmax exp(x) becomes exp2(score*sph)
#define QSCALE 0.1803368801111214f

typedef __attribute__((ext_vector_type(8))) short bf16x8;
typedef __attribute__((ext_vector_type(4))) float f32x4;

__device__ inline unsigned short f2bf(float f) {
    union { float f; unsigned int u; } a; a.f = f;
    unsigned int u = a.u;
    u += 0x7FFFu + ((u >> 16) & 1u);   // RNE
    return (unsigned short)(u >> 16);
}

// async global->LDS, 16B per lane. LDS dest must be linear in lane id.
#define GLL(g, l) __builtin_amdgcn_global_load_lds( \
    (const __attribute__((address_space(1))) unsigned int*)(g), \
    (__attribute__((address_space(3))) unsigned int*)(l), 16, 0, 0)

__device__ inline void cvt8(const float* s, unsigned short* d) {
    const float4* sp = (const float4*)s;
    float4 v0 = sp[0], v1 = sp[1];
    union { bf16x8 v; unsigned short s[8]; } u;
    u.s[0]=f2bf(v0.x); u.s[1]=f2bf(v0.y); u.s[2]=f2bf(v0.z); u.s[3]=f2bf(v0.w);
    u.s[4]=f2bf(v1.x); u.s[5]=f2bf(v1.y); u.s[6]=f2bf(v1.z); u.s[7]=f2bf(v1.w);
    *(bf16x8*)d = u.v;
}

// ---------------------------------------------------------------------------
// fp32 -> bf16 conversion for query/key/value and the 4 weight matrices.
// ---------------------------------------------------------------------------
__global__ __launch_bounds__(256) void cvt7_kernel(
    const float* __restrict__ q, const float* __restrict__ k, const float* __restrict__ v,
    const float* __restrict__ wq, const float* __restrict__ wk,
    const float* __restrict__ wv, const float* __restrict__ wo,
    unsigned short* __restrict__ qB, unsigned short* __restrict__ kB,
    unsigned short* __restrict__ vB, unsigned short* __restrict__ WB)
{
    int e = (blockIdx.x * 256 + threadIdx.x) * 8;
    if (e < NBIG)            cvt8(q + e, qB + e);
    else if (e < 2*NBIG)     cvt8(k + (e - NBIG), kB + (e - NBIG));
    else if (e < 3*NBIG)     cvt8(v + (e - 2*NBIG), vB + (e - 2*NBIG));
    else {
        int w = e - 3*NBIG;            // 0 .. 4*NW
        int wi = w >> 18;              // NW = 2^18
        int off = w & (NW - 1);
        const float* src = wi == 0 ? wq : wi == 1 ? wk : wi == 2 ? wv : wo;
        cvt8(src + off, WB + w);
    }
}

// ---------------------------------------------------------------------------
// Fused Q/K/V projection GEMM, double-buffered global_load_lds, 1 barrier/iter.
// Grid (192, 8): blockIdx.x = seg*64 + row-tile, seg 0/1/2 = q/k/v.
// ---------------------------------------------------------------------------
__global__ __launch_bounds__(256) void qkv_gemm(
    const unsigned short* __restrict__ qB, const unsigned short* __restrict__ kB,
    const unsigned short* __restrict__ vB, const unsigned short* __restrict__ WB,
    const float* __restrict__ bq, const float* __restrict__ bk, const float* __restrict__ bv,
    unsigned short* __restrict__ q_ws, unsigned short* __restrict__ k_ws,
    unsigned short* __restrict__ vT_ws)
{
    __shared__ unsigned short A_lds[2][64][32];
    __shared__ unsigned short B_lds[2][64][32];

    const int t    = threadIdx.x;
    const int lane = t & 63;
    const int wave = t >> 6;
    const int wm   = wave >> 1, wn = wave & 1;
    const int lrow = lane & 15, lgr = lane >> 4;
    const int seg  = blockIdx.x >> 6;
    const int bm   = blockIdx.x & 63;
    const int bn   = blockIdx.y;

    const unsigned short* A    = seg == 0 ? qB : seg == 1 ? kB : vB;
    const unsigned short* W    = WB + (size_t)seg * NW;
    const float*          bias = seg == 0 ? bq : seg == 1 ? bk : bv;
    unsigned short*       Cp   = seg == 0 ? q_ws : seg == 1 ? k_ws : vT_ws;

    f32x4 acc[2][2] = {};

    const unsigned short* Ag = A + (size_t)(bm*64 + (t>>2))*512 + (t&3)*8;
    const unsigned short* Wg = W + (size_t)(bn*64 + (t>>2))*512 + (t&3)*8;
    unsigned short* lA0 = &A_lds[0][t>>2][(t&3)*8];
    unsigned short* lA1 = &A_lds[1][t>>2][(t&3)*8];
    unsigned short* lB0 = &B_lds[0][t>>2][(t&3)*8];
    unsigned short* lB1 = &B_lds[1][t>>2][(t&3)*8];

    GLL(Ag, lA0);
    GLL(Wg, lB0);

    for (int kk = 0; kk < 512; kk += 32) {
        const int buf = (kk >> 5) & 1;
        __syncthreads();   // drains vmcnt -> buf ready (loads issued 1 phase ago)
        if (kk < 480) {
            GLL(Ag + kk + 32, buf ? lA0 : lA1);
            GLL(Wg + kk + 32, buf ? lB0 : lB1);
        }

        bf16x8 a0 = *(const bf16x8*)&A_lds[buf][wm*32 +      lrow][lgr*8];
        bf16x8 a1 = *(const bf16x8*)&A_lds[buf][wm*32 + 16 + lrow][lgr*8];
        bf16x8 b0 = *(const bf16x8*)&B_lds[buf][wn*32 +      lrow][lgr*8];
        bf16x8 b1 = *(const bf16x8*)&B_lds[buf][wn*32 + 16 + lrow][lgr*8];

        acc[0][0] = __builtin_amdgcn_mfma_f32_16x16x32_bf16(a0, b0, acc[0][0], 0, 0, 0);
        acc[0][1] = __builtin_amdgcn_mfma_f32_16x16x32_bf16(a0, b1, acc[0][1], 0, 0, 0);
        acc[1][0] = __builtin_amdgcn_mfma_f32_16x16x32_bf16(a1, b0, acc[1][0], 0, 0, 0);
        acc[1][1] = __builtin_amdgcn_mfma_f32_16x16x32_bf16(a1, b1, acc[1][1], 0, 0, 0);
    }

    #pragma unroll
    for (int mf = 0; mf < 2; ++mf)
    #pragma unroll
    for (int nf = 0; nf < 2; ++nf)
    #pragma unroll
    for (int r = 0; r < 4; ++r) {
        int grow = bm*64 + wm*32 + mf*16 + lgr*4 + r;
        int gcol = bn*64 + wn*32 + nf*16 + lrow;
        float v = acc[mf][nf][r] + bias[gcol];
        if (seg == 0) v *= QSCALE;
        int bb = grow >> 11, s = grow & 2047;
        int hh = gcol >> 6,  dk = gcol & 63;
        unsigned short bv16 = f2bf(v);
        if (seg < 2)
            Cp[((size_t)(bb*H_ + hh)*S_ + s)*DK_ + dk] = bv16;
        else
            Cp[((size_t)(bb*H_ + hh)*DK_ + dk)*S_ + s] = bv16;
    }
}

// ---------------------------------------------------------------------------
// Output projection GEMM: fp32 out = attn(bf16) @ Wo^T + bo.
// ---------------------------------------------------------------------------
__global__ __launch_bounds__(256) void out_gemm(
    const unsigned short* __restrict__ A,
    const unsigned short* __restrict__ W,
    const float* __restrict__ bias,
    float* __restrict__ C)
{
    __shared__ unsigned short A_lds[2][64][32];
    __shared__ unsigned short B_lds[2][64][32];

    const int t    = threadIdx.x;
    const int lane = t & 63;
    const int wave = t >> 6;
    const int wm   = wave >> 1, wn = wave & 1;
    const int lrow = lane & 15, lgr = lane >> 4;
    const int bm   = blockIdx.x, bn = blockIdx.y;

    f32x4 acc[2][2] = {};

    const unsigned short* Ag = A + (size_t)(bm*64 + (t>>2))*512 + (t&3)*8;
    const unsigned short* Wg = W + (size_t)(bn*64 + (t>>2))*512 + (t&3)*8;
    unsigned short* lA0 = &A_lds[0][t>>2][(t&3)*8];
    unsigned short* lA1 = &A_lds[1][t>>2][(t&3)*8];
    unsigned short* lB0 = &B_lds[0][t>>2][(t&3)*8];
    unsigned short* lB1 = &B_lds[1][t>>2][(t&3)*8];

    GLL(Ag, lA0);
    GLL(Wg, lB0);

    for (int kk = 0; kk < 512; kk += 32) {
        const int buf = (kk >> 5) & 1;
        __syncthreads();
        if (kk < 480) {
            GLL(Ag + kk + 32, buf ? lA0 : lA1);
            GLL(Wg + kk + 32, buf ? lB0 : lB1);
        }

        bf16x8 a0 = *(const bf16x8*)&A_lds[buf][wm*32 +      lrow][lgr*8];
        bf16x8 a1 = *(const bf16x8*)&A_lds[buf][wm*32 + 16 + lrow][lgr*8];
        bf16x8 b0 = *(const bf16x8*)&B_lds[buf][wn*32 +      lrow][lgr*8];
        bf16x8 b1 = *(const bf16x8*)&B_lds[buf][wn*32 + 16 + lrow][lgr*8];

        acc[0][0] = __builtin_amdgcn_mfma_f32_16x16x32_bf16(a0, b0, acc[0][0], 0, 0, 0);
        acc[0][1] = __builtin_amdgcn_mfma_f32_16x16x32_bf16(a0, b1, acc[0][1], 0, 0, 0);
        acc[1][0] = __builtin_amdgcn_mfma_f32_16x16x32_bf16(a1, b0, acc[1][0], 0, 0, 0);
        acc[1][1] = __builtin_amdgcn_mfma_f32_16x16x32_bf16(a1, b1, acc[1][1], 0, 0, 0);
    }

    #pragma unroll
    for (int mf = 0; mf < 2; ++mf)
    #pragma unroll
    for (int nf = 0; nf < 2; ++nf)
    #pragma unroll
    for (int r = 0; r < 4; ++r) {
        int grow = bm*64 + wm*32 + mf*16 + lgr*4 + r;
        int gcol = bn*64 + wn*32 + nf*16 + lrow;
        C[(size_t)grow*512 + gcol] = acc[mf][nf][r] + bias[gcol];
    }
}

// ---------------------------------------------------------------------------
// Attention, no-max softmax via exp2 (log2e folded into Q scale).
// Split-K across wave halves, 512 threads = 8 waves, pad-68 LDS (0 bank
// conflicts measured). launch_bounds (512,4): VGPR ~52, NO spills (the
// (512,6) variant forced VGPR=40 -> 63MB scratch traffic, +40us).
// ---------------------------------------------------------------------------
__global__ __launch_bounds__(512, 4) void attn_fast(
    const unsigned short* __restrict__ q_ws,
    const unsigned short* __restrict__ k_ws,
    const unsigned short* __restrict__ vT_ws,
    const float* __restrict__ sph,
    unsigned short* __restrict__ attn_ws)
{
    __shared__ unsigned short K_lds[2][64][68];
    __shared__ unsigned short V_lds[2][64][68];
    __shared__ unsigned short P_lds[8][16][68];
    __shared__ float l_sh[8][16];
    // O_sh overlays K_lds (dead after main loop): 4*16*68*4 = 17408 = sizeof(K_lds)
    float (*O_sh)[16][68] = (float (*)[16][68])(&K_lds[0][0][0]);

    const int t    = threadIdx.x;
    const int lane = t & 63, wave = t >> 6;
    const int lrow = lane & 15, lgr = lane >> 4;
    const int wq = wave & 3;      // q sub-tile (16 rows)
    const int wh = wave >> 2;     // k half
    const int qt = blockIdx.x, bh = blockIdx.y;
    const int b  = bh >> 3;
    const int h  = bh & 7;
    const int qbase = qt * 64;
    const size_t head_off = (size_t)bh * S_ * DK_;

    bf16x8 qf0, qf1;
    {
        const unsigned short* qp =
            q_ws + head_off + (size_t)(qbase + wq*16 + lrow)*DK_ + lgr*8;
        qf0 = *(const bf16x8*)qp;
        qf1 = *(const bf16x8*)(qp + 32);
    }

    const int sh = t >> 8;
    const int sr = (t >> 2) & 63;
    const int sc = (t & 3) * 16;
    const unsigned short* kstage = k_ws  + head_off + ((size_t)sh*1024 + sr)*DK_ + sc;
    const unsigned short* vstage = vT_ws + head_off + (size_t)sr*S_ + sh*1024 + sc;

    const float* sphb   = sph + (size_t)b * S_ * S_;
    const float* sph_p0 = sphb + (size_t)(qbase + wq*16 + lgr*4 + 0)*S_ + wh*1024 + lrow;
    const float* sph_p1 = sph_p0 + S_;
    const float* sph_p2 = sph_p0 + 2*S_;
    const float* sph_p3 = sph_p0 + 3*S_;

    f32x4 acc_o[4] = {};
    float psum[4] = {0.f, 0.f, 0.f, 0.f};

    // prologue: stage tile 0 + sph tile 0
    bf16x8 kr0 = *(const bf16x8*)(kstage);
    bf16x8 kr1 = *(const bf16x8*)(kstage + 8);
    bf16x8 vr0 = *(const bf16x8*)(vstage);
    bf16x8 vr1 = *(const bf16x8*)(vstage + 8);
    *(bf16x8*)&K_lds[sh][sr][sc]     = kr0;
    *(bf16x8*)&K_lds[sh][sr][sc + 8] = kr1;
    *(bf16x8*)&V_lds[sh][sr][sc]     = vr0;
    *(bf16x8*)&V_lds[sh][sr][sc + 8] = vr1;

    float sphr[4][4];
    #pragma unroll
    for (int nf = 0; nf < 4; ++nf) {
        sphr[nf][0] = sph_p0[nf*16];
        sphr[nf][1] = sph_p1[nf*16];
        sphr[nf][2] = sph_p2[nf*16];
        sphr[nf][3] = sph_p3[nf*16];
    }

    for (int kt = 0; kt < 16; ++kt) {
        __syncthreads();   // LDS tile kt ready

        if (kt < 15) {     // next-tile K/V register prefetch
            const unsigned short* kp = kstage + (size_t)(kt+1)*64*DK_;
            const unsigned short* vp = vstage + (kt+1)*64;
            kr0 = *(const bf16x8*)(kp);
            kr1 = *(const bf16x8*)(kp + 8);
            vr0 = *(const bf16x8*)(vp);
            vr1 = *(const bf16x8*)(vp + 8);
        }

        // QK^T: 16 q rows x 64 k cols per wave
        f32x4 sc4[4];
        __builtin_amdgcn_s_setprio(1);
        #pragma unroll
        for (int nf = 0; nf < 4; ++nf) {
            bf16x8 kf0 = *(const bf16x8*)&K_lds[wh][nf*16 + lrow][lgr*8];
            bf16x8 kf1 = *(const bf16x8*)&K_lds[wh][nf*16 + lrow][32 + lgr*8];
            f32x4 a = {};
            a = __builtin_amdgcn_mfma_f32_16x16x32_bf16(qf0, kf0, a, 0, 0, 0);
            a = __builtin_amdgcn_mfma_f32_16x16x32_bf16(qf1, kf1, a, 0, 0, 0);
            sc4[nf] = a;
        }
        __builtin_amdgcn_s_setprio(0);

        // p = exp2(score * sph); row-sum partials
        #pragma unroll
        for (int nf = 0; nf < 4; ++nf)
        #pragma unroll
        for (int r = 0; r < 4; ++r) {
            float p = __builtin_amdgcn_exp2f(sc4[nf][r] * sphr[nf][r]);
            sc4[nf][r] = p;
            psum[r] += p;
        }

        // P -> bf16 -> per-wave LDS (wave-private: no barrier needed)
        #pragma unroll
        for (int nf = 0; nf < 4; ++nf)
        #pragma unroll
        for (int r = 0; r < 4; ++r)
            P_lds[wave][lgr*4 + r][nf*16 + lrow] = f2bf(sc4[nf][r]);

        if (kt < 15) {     // next-tile sph prefetch (hides under PV)
            const int off = (kt + 1) * 64;
            #pragma unroll
            for (int nf = 0; nf < 4; ++nf) {
                sphr[nf][0] = sph_p0[off + nf*16];
                sphr[nf][1] = sph_p1[off + nf*16];
                sphr[nf][2] = sph_p2[off + nf*16];
                sphr[nf][3] = sph_p3[off + nf*16];
            }
        }

        // PV: acc_o[nb] += P @ V  (unnormalized accumulate)
        __builtin_amdgcn_s_setprio(1);
        #pragma unroll
        for (int ks2 = 0; ks2 < 2; ++ks2) {
            bf16x8 pf = *(const bf16x8*)&P_lds[wave][lrow][ks2*32 + lgr*8];
            #pragma unroll
            for (int nb = 0; nb < 4; ++nb) {
                bf16x8 vf = *(const bf16x8*)&V_lds[wh][nb*16 + lrow][ks2*32 + lgr*8];
                acc_o[nb] = __builtin_amdgcn_mfma_f32_16x16x32_bf16(pf, vf, acc_o[nb], 0, 0, 0);
            }
        }
        __builtin_amdgcn_s_setprio(0);
        __syncthreads();   // all K/V_lds reads done

        if (kt < 15) {
            *(bf16x8*)&K_lds[sh][sr][sc]     = kr0;
            *(bf16x8*)&K_lds[sh][sr][sc + 8] = kr1;
            *(bf16x8*)&V_lds[sh][sr][sc]     = vr0;
            *(bf16x8*)&V_lds[sh][sr][sc + 8] = vr1;
        }
    }

    // one-time row-sum reduce (over lrow lanes within each lgr group)
    #pragma unroll
    for (int off = 1; off < 16; off <<= 1)
        #pragma unroll
        for (int r = 0; r < 4; ++r)
            psum[r] += __shfl_xor(psum[r], off, 64);

    if (lrow == 0) {
        #pragma unroll
        for (int r = 0; r < 4; ++r)
            l_sh[wave][lgr*4 + r] = psum[r];
    }
    __syncthreads();

    float linv[4];
    #pragma unroll
    for (int r = 0; r < 4; ++r) {
        int row = lgr*4 + r;
        linv[r] = 1.f / (l_sh[wq][row] + l_sh[wq + 4][row]);
    }
    if (wh == 1) {
        #pragma unroll
        for (int nb = 0; nb < 4; ++nb)
        #pragma unroll
        for (int r = 0; r < 4; ++r)
            O_sh[wq][lgr*4 + r][nb*16 + lrow] = acc_o[nb][r];
    }
    __syncthreads();
    if (wh == 0) {
        #pragma unroll
        for (int nb = 0; nb < 4; ++nb)
        #pragma unroll
        for (int r = 0; r < 4; ++r) {
            int qrow = qbase + wq*16 + lgr*4 + r;
            float o = (acc_o[nb][r] + O_sh[wq][lgr*4 + r][nb*16 + lrow]) * linv[r];
            attn_ws[((size_t)(b*S_) + qrow)*D_ + h*64 + nb*16 + lrow] = f2bf(o);
        }
    }
}

// ===========================================================================
// Fallback path (proven): used only if ws_size < 26 MiB.
// ===========================================================================
template<int A_BF16, int MODE>
__global__ __launch_bounds__(256) void gemm_old(
    const void* __restrict__ Aptr,
    const float* __restrict__ W,
    const float* __restrict__ bias,
    void* __restrict__ Cptr)
{
    __shared__ unsigned short A_lds[64][40];
    __shared__ unsigned short B_lds[64][40];

    const int t    = threadIdx.x;
    const int lane = t & 63;
    const int wave = t >> 6;
    const int wm   = wave >> 1, wn = wave & 1;
    const int lrow = lane & 15, lgr = lane >> 4;
    const int bm   = blockIdx.x, bn = blockIdx.y;

    f32x4 acc[2][2] = {};
    const int srow = t >> 2;
    const int scol = (t & 3) * 8;

    for (int kk = 0; kk < 512; kk += 32) {
        if (A_BF16) {
            const unsigned short* A = (const unsigned short*)Aptr;
            bf16x8 v = *(const bf16x8*)(A + (size_t)(bm*64 + srow)*512 + kk + scol);
            *(bf16x8*)&A_lds[srow][scol] = v;
        } else {
            const float* A = (const float*)Aptr;
            cvt8(A + (size_t)(bm*64 + srow)*512 + kk + scol, &A_lds[srow][scol]);
        }
        cvt8(W + (size_t)(bn*64 + srow)*512 + kk + scol, &B_lds[srow][scol]);
        __syncthreads();

        bf16x8 a0 = *(const bf16x8*)&A_lds[wm*32 +      lrow][lgr*8];
        bf16x8 a1 = *(const bf16x8*)&A_lds[wm*32 + 16 + lrow][lgr*8];
        bf16x8 b0 = *(const bf16x8*)&B_lds[wn*32 +      lrow][lgr*8];
        bf16x8 b1 = *(const bf16x8*)&B_lds[wn*32 + 16 + lrow][lgr*8];

        acc[0][0] = __builtin_amdgcn_mfma_f32_16x16x32_bf16(a0, b0, acc[0][0], 0, 0, 0);
        acc[0][1] = __builtin_amdgcn_mfma_f32_16x16x32_bf16(a0, b1, acc[0][1], 0, 0, 0);
        acc[1][0] = __builtin_amdgcn_mfma_f32_16x16x32_bf16(a1, b0, acc[1][0], 0, 0, 0);
        acc[1][1] = __builtin_amdgcn_mfma_f32_16x16x32_bf16(a1, b1, acc[1][1], 0, 0, 0);
        __syncthreads();
    }

    #pragma unroll
    for (int mf = 0; mf < 2; ++mf)
    #pragma unroll
    for (int nf = 0; nf < 2; ++nf)
    #pragma unroll
    for (int r = 0; r < 4; ++r) {
        int grow = bm*64 + wm*32 + mf*16 + lgr*4 + r;
        int gcol = bn*64 + wn*32 + nf*16 + lrow;
        float v = acc[mf][nf][r] + bias[gcol];
        if (MODE == 2) {
            ((float*)Cptr)[(size_t)grow*512 + gcol] = v;
        } else {
            int bb = grow >> 11, s = grow & 2047;
            int hh = gcol >> 6,  dk = gcol & 63;
            unsigned short bv = f2bf(v);
            if (MODE == 0)
                ((unsigned short*)Cptr)[((size_t)(bb*H_ + hh)*S_ + s)*DK_ + dk] = bv;
            else
                ((unsigned short*)Cptr)[((size_t)(bb*H_ + hh)*DK_ + dk)*S_ + s] = bv;
        }
    }
}

__global__ __launch_bounds__(512, 4) void attn_old(
    const unsigned short* __restrict__ q_ws,
    const unsigned short* __restrict__ k_ws,
    const unsigned short* __restrict__ vT_ws,
    const float* __restrict__ sph,
    unsigned short* __restrict__ attn_ws)
{
    __shared__ unsigned short K_lds[2][64][72];
    __shared__ unsigned short V_lds[2][64][72];
    __shared__ unsigned short P_lds[8][16][72];
    __shared__ float m_sh[8][16];
    __shared__ float l_sh[8][16];
    __shared__ float O_sh[4][16][68];

    const int t    = threadIdx.x;
    const int lane = t & 63, wave = t >> 6;
    const int lrow = lane & 15, lgr = lane >> 4;
    const int wq = wave & 3;
    const int wh = wave >> 2;
    const int qt = blockIdx.x, bh = blockIdx.y;
    const int b  = bh >> 3;
    const int h  = bh & 7;
    const int qbase = qt * 64;
    const size_t head_off = (size_t)bh * S_ * DK_;

    bf16x8 qf0, qf1;
    {
        const unsigned short* qp =
            q_ws + head_off + (size_t)(qbase + wq*16 + lrow)*DK_ + lgr*8;
        qf0 = *(const bf16x8*)qp;
        qf1 = *(const bf16x8*)(qp + 32);
    }

    const int sh = t >> 8;
    const int sr = (t >> 2) & 63;
    const int sc = (t & 3) * 16;
    const unsigned short* kstage = k_ws  + head_off + ((size_t)sh*1024 + sr)*DK_ + sc;
    const unsigned short* vstage = vT_ws + head_off + (size_t)sr*S_ + sh*1024 + sc;

    const float* sphb   = sph + (size_t)b * S_ * S_;
    const float* sph_p0 = sphb + (size_t)(qbase + wq*16 + lgr*4 + 0)*S_ + wh*1024 + lrow;
    const float* sph_p1 = sph_p0 + S_;
    const float* sph_p2 = sph_p0 + 2*S_;
    const float* sph_p3 = sph_p0 + 3*S_;

    f32x4 acc_o[4] = {};
    float m_run[4] = {-INFINITY,-INFINITY,-INFINITY,-INFINITY};
    float l_run[4] = {0.f,0.f,0.f,0.f};

    bf16x8 kr0 = *(const bf16x8*)(kstage);
    bf16x8 kr1 = *(const bf16x8*)(kstage + 8);
    bf16x8 vr0 = *(const bf16x8*)(vstage);
    bf16x8 vr1 = *(const bf16x8*)(vstage + 8);
    *(bf16x8*)&K_lds[sh][sr][sc]     = kr0;
    *(bf16x8*)&K_lds[sh][sr][sc + 8] = kr1;
    *(bf16x8*)&V_lds[sh][sr][sc]     = vr0;
    *(bf16x8*)&V_lds[sh][sr][sc + 8] = vr1;

    float sphr[4][4];
    #pragma unroll
    for (int nf = 0; nf < 4; ++nf) {
        sphr[nf][0] = sph_p0[nf*16];
        sphr[nf][1] = sph_p1[nf*16];
        sphr[nf][2] = sph_p2[nf*16];
        sphr[nf][3] = sph_p3[nf*16];
    }

    for (int kt = 0; kt < 16; ++kt) {
        __syncthreads();

        if (kt < 15) {
            const unsigned short* kp = kstage + (size_t)(kt+1)*64*DK_;
            const unsigned short* vp = vstage + (kt+1)*64;
            kr0 = *(const bf16x8*)(kp);
            kr1 = *(const bf16x8*)(kp + 8);
            vr0 = *(const bf16x8*)(vp);
            vr1 = *(const bf16x8*)(vp + 8);
        }

        f32x4 sc4[4];
        #pragma unroll
        for (int nf = 0; nf < 4; ++nf) {
            bf16x8 kf0 = *(const bf16x8*)&K_lds[wh][nf*16 + lrow][lgr*8];
            bf16x8 kf1 = *(const bf16x8*)&K_lds[wh][nf*16 + lrow][32 + lgr*8];
            f32x4 a = {};
            a = __builtin_amdgcn_mfma_f32_16x16x32_bf16(qf0, kf0, a, 0, 0, 0);
            a = __builtin_amdgcn_mfma_f32_16x16x32_bf16(qf1, kf1, a, 0, 0, 0);
            sc4[nf] = a;
        }

        float pmax[4] = {-INFINITY,-INFINITY,-INFINITY,-INFINITY};
        #pragma unroll
        for (int nf = 0; nf < 4; ++nf)
        #pragma unroll
        for (int r = 0; r < 4; ++r) {
            float s = sc4[nf][r] * 0.125f * sphr[nf][r];
            sc4[nf][r] = s;
            pmax[r] = fmaxf(pmax[r], s);
        }
        #pragma unroll
        for (int off = 1; off < 16; off <<= 1)
            #pragma unroll
            for (int r = 0; r < 4; ++r)
                pmax[r] = fmaxf(pmax[r], __shfl_xor(pmax[r], off, 64));

        float sc_old[4], psum[4] = {0.f,0.f,0.f,0.f};
        #pragma unroll
        for (int r = 0; r < 4; ++r) {
            float mn = fmaxf(m_run[r], pmax[r]);
            sc_old[r] = __expf(m_run[r] - mn);
            m_run[r] = mn;
        }
        #pragma unroll
        for (int nf = 0; nf < 4; ++nf)
        #pragma unroll
        for (int r = 0; r < 4; ++r) {
            float p = __expf(sc4[nf][r] - m_run[r]);
            sc4[nf][r] = p;
            psum[r] += p;
        }
        #pragma unroll
        for (int off = 1; off < 16; off <<= 1)
            #pragma unroll
            for (int r = 0; r < 4; ++r)
                psum[r] += __shfl_xor(psum[r], off, 64);
        #pragma unroll
        for (int r = 0; r < 4; ++r)
            l_run[r] = l_run[r] * sc_old[r] + psum[r];
        #pragma unroll
        for (int nb = 0; nb < 4; ++nb)
            #pragma unroll
            for (int r = 0; r < 4; ++r)
                acc_o[nb][r] *= sc_old[r];

        #pragma unroll
        for (int nf = 0; nf < 4; ++nf)
        #pragma unroll
        for (int r = 0; r < 4; ++r)
            P_lds[wave][lgr*4 + r][nf*16 + lrow] = f2bf(sc4[nf][r]);
        __syncthreads();

        #pragma unroll
        for (int ks2 = 0; ks2 < 2; ++ks2) {
            bf16x8 pf = *(const bf16x8*)&P_lds[wave][lrow][ks2*32 + lgr*8];
            #pragma unroll
            for (int nb = 0; nb < 4; ++nb) {
                bf16x8 vf = *(const bf16x8*)&V_lds[wh][nb*16 + lrow][ks2*32 + lgr*8];
                acc_o[nb] = __builtin_amdgcn_mfma_f32_16x16x32_bf16(pf, vf, acc_o[nb], 0, 0, 0);
            }
        }

        if (kt < 15) {
            const int off = (kt + 1) * 64;
            #pragma unroll
            for (int nf = 0; nf < 4; ++nf) {
                sphr[nf][0] = sph_p0[off + nf*16];
                sphr[nf][1] = sph_p1[off + nf*16];
                sphr[nf][2] = sph_p2[off + nf*16];
                sphr[nf][3] = sph_p3[off + nf*16];
            }
        }
        __syncthreads();

        if (kt < 15) {
            *(bf16x8*)&K_lds[sh][sr][sc]     = kr0;
            *(bf16x8*)&K_lds[sh][sr][sc + 8] = kr1;
            *(bf16x8*)&V_lds[sh][sr][sc]     = vr0;
            *(bf16x8*)&V_lds[sh][sr][sc + 8] = vr1;
        }
    }

    if (lrow == 0) {
        #pragma unroll
        for (int r = 0; r < 4; ++r) {
            m_sh[wave][lgr*4 + r] = m_run[r];
            l_sh[wave][lgr*4 + r] = l_run[r];
        }
    }
    __syncthreads();

    float scl[4], lcomb[4];
    #pragma unroll
    for (int r = 0; r < 4; ++r) {
        int row = lgr*4 + r;
        float m0 = m_sh[wq][row],     m1 = m_sh[wq + 4][row];
        float l0 = l_sh[wq][row],     l1 = l_sh[wq + 4][row];
        float mm = fmaxf(m0, m1);
        float s0 = __expf(m0 - mm),   s1 = __expf(m1 - mm);
        lcomb[r] = l0*s0 + l1*s1;
        scl[r]   = (wh == 0) ? s0 : s1;
    }
    if (wh == 1) {
        #pragma unroll
        for (int nb = 0; nb < 4; ++nb)
        #pragma unroll
        for (int r = 0; r < 4; ++r)
            O_sh[wq][lgr*4 + r][nb*16 + lrow] = acc_o[nb][r] * scl[r];
    }
    __syncthreads();
    if (wh == 0) {
        #pragma unroll
        for (int nb = 0; nb < 4; ++nb)
        #pragma unroll
        for (int r = 0; r < 4; ++r) {
            int qrow = qbase + wq*16 + lgr*4 + r;
            float o = (acc_o[nb][r]*scl[r] + O_sh[wq][lgr*4 + r][nb*16 + lrow]) / lcomb[r];
            attn_ws[((size_t)(b*S_) + qrow)*D_ + h*64 + nb*16 + lrow] = f2bf(o);
        }
    }
}

// ---------------------------------------------------------------------------
extern "C" void kernel_launch(void* const* d_in, const int* in_sizes, int n_in,
                              void* d_out, int out_size, void* d_ws, size_t ws_size,
                              hipStream_t stream) {
    (void)in_sizes; (void)n_in; (void)out_size;
    const float* query = (const float*)d_in[0];
    const float* key_  = (const float*)d_in[1];
    const float* value = (const float*)d_in[2];
    const float* sph   = (const float*)d_in[3];
    const float* Wq = (const float*)d_in[4];
    const float* bq = (const float*)d_in[5];
    const float* Wk = (const float*)d_in[6];
    const float* bk = (const float*)d_in[7];
    const float* Wv = (const float*)d_in[8];
    const float* bv = (const float*)d_in[9];
    const float* Wo = (const float*)d_in[10];
    const float* bo = (const float*)d_in[11];

    char* ws = (char*)d_ws;
    const size_t MB = 1024*1024;
    const size_t NEED = 26*MB;

    if (ws_size >= NEED) {
        // layout: [0 qB/attn_ws][4 kB][8 vB][12 WB(2MB)][14 q_ws][18 k_ws][22 vT_ws]
        unsigned short* qB      = (unsigned short*)(ws);
        unsigned short* kB      = (unsigned short*)(ws + 4*MB);
        unsigned short* vB      = (unsigned short*)(ws + 8*MB);
        unsigned short* WB      = (unsigned short*)(ws + 12*MB);
        unsigned short* q_ws    = (unsigned short*)(ws + 14*MB);
        unsigned short* k_ws    = (unsigned short*)(ws + 18*MB);
        unsigned short* vT_ws   = (unsigned short*)(ws + 22*MB);
        unsigned short* attn_ws = qB;   // qB dead after its GEMM

        cvt7_kernel<<<3584, 256, 0, stream>>>(query, key_, value, Wq, Wk, Wv, Wo,
                                              qB, kB, vB, WB);
        qkv_gemm<<<dim3(192, 8), 256, 0, stream>>>(qB, kB, vB, WB, bq, bk, bv,
                                                   q_ws, k_ws, vT_ws);
        attn_fast<<<dim3(S_/64, B_*H_), 512, 0, stream>>>(q_ws, k_ws, vT_ws, sph, attn_ws);
        out_gemm<<<dim3(64, 8), 256, 0, stream>>>(attn_ws, WB + 3*(size_t)NW, bo, (float*)d_out);
    } else {
        // fallback (needs 16 MiB)
        const size_t SEG = (size_t)M_ * D_ * 2;
        unsigned short* q_ws    = (unsigned short*)(ws);
        unsigned short* k_ws    = (unsigned short*)(ws + SEG);
        unsigned short* vT_ws   = (unsigned short*)(ws + 2*SEG);
        unsigned short* attn_ws = (unsigned short*)(ws + 3*SEG);

        dim3 gg(M_/64, D_/64);
        gemm_old<0, 0><<<gg, 256, 0, stream>>>(query, Wq, bq, q_ws);
        gemm_old<0, 0><<<gg, 256, 0, stream>>>(key_,  Wk, bk, k_ws);
        gemm_old<0, 1><<<gg, 256, 0, stream>>>(value, Wv, bv, vT_ws);
        attn_old<<<dim3(S_/64, B_*H_), 512, 0, stream>>>(q_ws, k_ws, vT_ws, sph, attn_ws);
        gemm_old<1, 2><<<gg, 256, 0, stream>>>(attn_ws, Wo, bo, (float*)d_out);
    }
}